// Round 2
// baseline (714.547 us; speedup 1.0000x reference)
//
#include <hip/hip_runtime.h>

// out[b,co,oh,ow] = bias[s,co] + sum_{ci,kh,kw} x[b,ci,oh+kh-2,ow+kw-2]*w[s,co,ci,kh,kw]
//   s = 2*(oh%4) + (ow%2); zero pad outside [0,720)x[0,1280).
// MFMA formulation: per parity class s, GEMM with M=pixels, N=64 co, K padded to 128:
//   k = p*8 + j,  p = ci*5+kh (0..14 real, 15 pad), j = kw (0..4 real, 5..7 pad).
// Pad entries have ZERO weights, so A may carry arbitrary finite x values there.

typedef __attribute__((ext_vector_type(8))) short bf16x8;
typedef __attribute__((ext_vector_type(4))) float f32x4;

static __device__ __forceinline__ unsigned short f2bf_rne(float f) {
    unsigned u = __builtin_bit_cast(unsigned, f);
    u += 0x7FFFu + ((u >> 16) & 1u);
    return (unsigned short)(u >> 16);
}

// wt2[s][p][co][j] bf16: 8*16*64*8 = 65536 elems = 128 KB
__global__ void wprep_kernel(const float* __restrict__ w, unsigned short* __restrict__ wt2) {
    int o = blockIdx.x * 256 + threadIdx.x;
    if (o >= 8 * 16 * 64 * 8) return;
    int j  = o & 7;
    int co = (o >> 3) & 63;
    int p  = (o >> 9) & 15;
    int s  = o >> 13;
    unsigned short v = 0;
    if (p < 15 && j < 5) {
        int ci = p / 5, kh = p % 5;
        v = f2bf_rne(w[((s * 64 + co) * 3 + ci) * 25 + kh * 5 + j]);
    }
    wt2[o] = v;
}

#define XS_W 265   // 263 needed; odd stride splits ds_read cohorts across bank parity
#define XS_R 8     // x rows 4bh-2 .. 4bh+5

__global__ __launch_bounds__(512, 4)
void conv_mfma_kernel(const float* __restrict__ x, const unsigned short* __restrict__ wt2,
                      const float* __restrict__ bias, float* __restrict__ out) {
    const int b   = blockIdx.z;
    const int bh  = blockIdx.y;        // output rows 4bh..4bh+3
    const int ow0 = blockIdx.x * 256;  // 256 output cols

    const int tid = threadIdx.x;
    __shared__ float xs[3 * XS_R * XS_W];   // 25440 B

    // ---- stage x tile (fp32, zero-padded halo) ----
    for (int idx = tid; idx < 3 * XS_R * XS_W; idx += 512) {
        int ci  = idx / (XS_R * XS_W);
        int rem = idx - ci * (XS_R * XS_W);
        int tt  = rem / XS_W;
        int u   = rem - tt * XS_W;
        int gr = 4 * bh - 2 + tt;
        int gc = ow0 - 2 + u;
        float v = 0.f;
        if ((unsigned)gr < 720u && (unsigned)gc < 1280u)
            v = x[((b * 3 + ci) * 720 + gr) * 1280 + gc];
        xs[idx] = v;
    }
    __syncthreads();

    const int wid  = tid >> 6;      // wave id = s = 2r+c
    const int lane = tid & 63;
    const int l15  = lane & 15;
    const int kg   = lane >> 4;     // k-group within MFMA
    const int r = wid >> 1, c = wid & 1;
    const int s = wid;

    // ---- B fragments: held in registers for the whole kernel (64 VGPRs) ----
    bf16x8 Bf[4][4];
    #pragma unroll
    for (int t = 0; t < 4; ++t) {
        #pragma unroll
        for (int n = 0; n < 4; ++n) {
            int p = 4 * t + kg;
            Bf[t][n] = *(const bf16x8*)(wt2 + (((s * 16 + p) * 64) + n * 16 + l15) * 8);
        }
    }

    float bv[4];
    #pragma unroll
    for (int n = 0; n < 4; ++n) bv[n] = bias[s * 64 + n * 16 + l15];

    // per-t LDS row base (bytes); pad group p==15 -> safe addr (weights are zero)
    int rowoff[4];
    #pragma unroll
    for (int t = 0; t < 4; ++t) {
        int p  = 4 * t + kg;
        int pp = (p < 15) ? p : 0;
        int ci = pp / 5, kh = pp - ci * 5;
        rowoff[t] = ((ci * XS_R + r + kh) * XS_W) * 4;
    }
    const int colbyte0 = (c + 2 * l15) * 4;

    const int oh = 4 * bh + r;
    // ow = ow0 + c + 2*(16g + 4*kg + reg)
    float* op0 = out + (((size_t)(b * 64 + l15) * 720 + oh) * 1280) + ow0 + c + 8 * kg;

    #pragma unroll 1
    for (int g = 0; g < 8; ++g) {
        f32x4 acc[4];
        #pragma unroll
        for (int n = 0; n < 4; ++n) { acc[n][0] = bv[n]; acc[n][1] = bv[n]; acc[n][2] = bv[n]; acc[n][3] = bv[n]; }

        const int cb = colbyte0 + g * 128;
        #pragma unroll
        for (int t = 0; t < 4; ++t) {
            const float* ap = (const float*)((const char*)xs + rowoff[t] + cb);
            float a0 = ap[0], a1 = ap[1], a2 = ap[2], a3 = ap[3];
            float a4 = ap[4], a5 = ap[5], a6 = ap[6], a7 = ap[7];
            unsigned d0, d1, d2, d3;
            asm("v_cvt_pk_bf16_f32 %0, %1, %2" : "=v"(d0) : "v"(a0), "v"(a1));
            asm("v_cvt_pk_bf16_f32 %0, %1, %2" : "=v"(d1) : "v"(a2), "v"(a3));
            asm("v_cvt_pk_bf16_f32 %0, %1, %2" : "=v"(d2) : "v"(a4), "v"(a5));
            asm("v_cvt_pk_bf16_f32 %0, %1, %2" : "=v"(d3) : "v"(a6), "v"(a7));
            union { unsigned u[4]; bf16x8 v; } ab;
            ab.u[0] = d0; ab.u[1] = d1; ab.u[2] = d2; ab.u[3] = d3;
            bf16x8 af = ab.v;
            #pragma unroll
            for (int n = 0; n < 4; ++n)
                acc[n] = __builtin_amdgcn_mfma_f32_16x16x32_bf16(af, Bf[t][n], acc[n], 0, 0, 0);
        }

        float* q = op0 + 32 * g;
        #pragma unroll
        for (int n = 0; n < 4; ++n) {
            float* qq = q + (size_t)n * 16 * 720 * 1280;
            qq[0] = acc[n][0];
            qq[2] = acc[n][1];
            qq[4] = acc[n][2];
            qq[6] = acc[n][3];
        }
    }
}

extern "C" void kernel_launch(void* const* d_in, const int* in_sizes, int n_in,
                              void* d_out, int out_size, void* d_ws, size_t ws_size,
                              hipStream_t stream) {
    const float* x    = (const float*)d_in[0];
    const float* w    = (const float*)d_in[1];
    const float* bias = (const float*)d_in[2];
    float* out = (float*)d_out;
    unsigned short* wt2 = (unsigned short*)d_ws;  // 128 KB

    wprep_kernel<<<dim3(256), dim3(256), 0, stream>>>(w, wt2);

    dim3 grid(1280 / 256, 720 / 4, 2);   // (ow tiles, oh tiles, batch)
    conv_mfma_kernel<<<grid, dim3(512), 0, stream>>>(x, wt2, bias, out);
}

// Round 3
// 518.855 us; speedup vs baseline: 1.3772x; 1.3772x over previous
//
#include <hip/hip_runtime.h>

// out[b,co,oh,ow] = bias[s,co] + sum_{ci,kh,kw} x[b,ci,oh+kh-2,ow+kw-2]*w[s,co,ci,kh,kw]
//   s = 2*(oh%4) + (ow%2); zero pad outside [0,720)x[0,1280).
// MFMA: A = weights (M=co16), B = pixels (N=16 even/odd ow positions), K=128:
//   k = p*8 + j, p = ci*5+kh (0..14 real, 15 pad), j = kw (0..4 real, 5..7 pad).
// One wave computes BOTH ow parities (two A weight-frag sets share one LDS read
// via j-shift), so each lane stores ow pairs as dwordx2 -> fully dense lines.

typedef __attribute__((ext_vector_type(8))) short bf16x8;
typedef __attribute__((ext_vector_type(4))) float f32x4;

static __device__ __forceinline__ unsigned short f2bf_rne(float f) {
    unsigned u = __builtin_bit_cast(unsigned, f);
    u += 0x7FFFu + ((u >> 16) & 1u);
    return (unsigned short)(u >> 16);
}

// wt2[s][p][co][j] bf16: 8*16*64*8 = 65536 elems = 128 KB
__global__ void wprep_kernel(const float* __restrict__ w, unsigned short* __restrict__ wt2) {
    int o = blockIdx.x * 256 + threadIdx.x;
    if (o >= 8 * 16 * 64 * 8) return;
    int j  = o & 7;
    int co = (o >> 3) & 63;
    int p  = (o >> 9) & 15;
    int s  = o >> 13;
    unsigned short v = 0;
    if (p < 15 && j < 5) {
        int ci = p / 5, kh = p % 5;
        v = f2bf_rne(w[((s * 64 + co) * 3 + ci) * 25 + kh * 5 + j]);
    }
    wt2[o] = v;
}

#define XS_W 264   // need 263 cols; even for 8B-aligned float2 LDS reads
#define XS_R 8     // x rows 4bh-2 .. 4bh+5

__global__ __launch_bounds__(256, 4)
void conv_mfma_kernel(const float* __restrict__ x, const unsigned short* __restrict__ wt2,
                      const float* __restrict__ bias, float* __restrict__ out) {
    const int zz  = blockIdx.z;
    const int b   = zz >> 2;
    const int cq  = zz & 3;            // co block: cq*16 .. cq*16+15
    const int bh  = blockIdx.y;        // output rows 4bh..4bh+3
    const int ow0 = blockIdx.x * 256;  // 256 output cols

    const int tid = threadIdx.x;
    __shared__ float xs[3 * XS_R * XS_W];   // 25344 B

    // ---- stage x tile (fp32, zero-padded halo) ----
    for (int idx = tid; idx < 3 * XS_R * XS_W; idx += 256) {
        int ci  = idx / (XS_R * XS_W);
        int rem = idx - ci * (XS_R * XS_W);
        int tt  = rem / XS_W;
        int u   = rem - tt * XS_W;
        int gr = 4 * bh - 2 + tt;
        int gc = ow0 - 2 + u;
        float v = 0.f;
        if ((unsigned)gr < 720u && (unsigned)gc < 1280u)
            v = x[((b * 3 + ci) * 720 + gr) * 1280 + gc];
        xs[idx] = v;
    }
    __syncthreads();

    const int r    = tid >> 6;     // wave id = output row phase 0..3
    const int lane = tid & 63;
    const int l15  = lane & 15;    // pixel index within MFMA (N), and co for A-frag load
    const int kg   = lane >> 4;    // k-octet
    const int cob  = cq * 16;

    // ---- A (weight) fragments, both parities: 32 VGPRs ----
    bf16x8 Wf[2][4];
    #pragma unroll
    for (int c = 0; c < 2; ++c) {
        #pragma unroll
        for (int t = 0; t < 4; ++t) {
            int p = 4 * t + kg;
            int s = 2 * r + c;
            Wf[c][t] = *(const bf16x8*)(wt2 + ((size_t)((s * 16 + p) * 64) + cob + l15) * 8);
        }
    }

    // bias for D rows co_sub = 4*kg + reg
    float bv[2][4];
    #pragma unroll
    for (int c = 0; c < 2; ++c)
        #pragma unroll
        for (int reg = 0; reg < 4; ++reg)
            bv[c][reg] = bias[(2 * r + c) * 64 + cob + 4 * kg + reg];

    // LDS row offsets (floats) per t; pad group p==15 -> any valid row (weights zero)
    int rowoff[4];
    #pragma unroll
    for (int t = 0; t < 4; ++t) {
        int p  = 4 * t + kg;
        int pp = (p < 15) ? p : 0;
        int ci = pp / 5, kh = pp - 5 * ci;
        rowoff[t] = (ci * XS_R + r + kh) * XS_W;
    }

    const int oh = 4 * bh + r;

    #pragma unroll 1
    for (int g = 0; g < 8; ++g) {
        f32x4 acc[2];
        #pragma unroll
        for (int c = 0; c < 2; ++c) {
            acc[c][0] = bv[c][0]; acc[c][1] = bv[c][1];
            acc[c][2] = bv[c][2]; acc[c][3] = bv[c][3];
        }

        const int colbase = 2 * l15 + 32 * g;   // even -> float2-aligned
        #pragma unroll
        for (int t = 0; t < 4; ++t) {
            const float* ap = xs + rowoff[t] + colbase;
            float v0, v1, v2, v3, v4, v5, v6, v7, v8, v9;
            { float2 f = *(const float2*)(ap + 0); v0 = f.x; v1 = f.y; }
            { float2 f = *(const float2*)(ap + 2); v2 = f.x; v3 = f.y; }
            { float2 f = *(const float2*)(ap + 4); v4 = f.x; v5 = f.y; }
            { float2 f = *(const float2*)(ap + 6); v6 = f.x; v7 = f.y; }
            { float2 f = *(const float2*)(ap + 8); v8 = f.x; v9 = f.y; }
            (void)v9;
            unsigned e0, e1, e2, e3, o0, o1, o2, o3;
            asm("v_cvt_pk_bf16_f32 %0, %1, %2" : "=v"(e0) : "v"(v0), "v"(v1));
            asm("v_cvt_pk_bf16_f32 %0, %1, %2" : "=v"(e1) : "v"(v2), "v"(v3));
            asm("v_cvt_pk_bf16_f32 %0, %1, %2" : "=v"(e2) : "v"(v4), "v"(v5));
            asm("v_cvt_pk_bf16_f32 %0, %1, %2" : "=v"(e3) : "v"(v6), "v"(v7));
            asm("v_cvt_pk_bf16_f32 %0, %1, %2" : "=v"(o0) : "v"(v1), "v"(v2));
            asm("v_cvt_pk_bf16_f32 %0, %1, %2" : "=v"(o1) : "v"(v3), "v"(v4));
            asm("v_cvt_pk_bf16_f32 %0, %1, %2" : "=v"(o2) : "v"(v5), "v"(v6));
            asm("v_cvt_pk_bf16_f32 %0, %1, %2" : "=v"(o3) : "v"(v7), "v"(v8));
            union { unsigned u[4]; bf16x8 v; } pe, po;
            pe.u[0] = e0; pe.u[1] = e1; pe.u[2] = e2; pe.u[3] = e3;
            po.u[0] = o0; po.u[1] = o1; po.u[2] = o2; po.u[3] = o3;
            acc[0] = __builtin_amdgcn_mfma_f32_16x16x32_bf16(Wf[0][t], pe.v, acc[0], 0, 0, 0);
            acc[1] = __builtin_amdgcn_mfma_f32_16x16x32_bf16(Wf[1][t], po.v, acc[1], 0, 0, 0);
        }

        // lane stores ow pair (ow0+32g+2*l15, +1) for 4 co-planes (reg)
        float* op = out + ((size_t)(b * 64 + cob + 4 * kg) * 720 + oh) * 1280
                        + ow0 + 32 * g + 2 * l15;
        #pragma unroll
        for (int reg = 0; reg < 4; ++reg) {
            float2 st; st.x = acc[0][reg]; st.y = acc[1][reg];
            *(float2*)(op + (size_t)reg * 720 * 1280) = st;
        }
    }
}

extern "C" void kernel_launch(void* const* d_in, const int* in_sizes, int n_in,
                              void* d_out, int out_size, void* d_ws, size_t ws_size,
                              hipStream_t stream) {
    const float* x    = (const float*)d_in[0];
    const float* w    = (const float*)d_in[1];
    const float* bias = (const float*)d_in[2];
    float* out = (float*)d_out;
    unsigned short* wt2 = (unsigned short*)d_ws;  // 128 KB

    wprep_kernel<<<dim3(256), dim3(256), 0, stream>>>(w, wt2);

    dim3 grid(1280 / 256, 720 / 4, 8);   // (ow tiles, oh tiles, b*4 + co-quarter)
    conv_mfma_kernel<<<grid, dim3(256), 0, stream>>>(x, wt2, bias, out);
}

// Round 5
// 516.931 us; speedup vs baseline: 1.3823x; 1.0037x over previous
//
#include <hip/hip_runtime.h>

// out[b,co,oh,ow] = bias[s,co] + sum_{ci,kh,kw} x[b,ci,oh+kh-2,ow+kw-2]*w[s,co,ci,kh,kw]
//   s = 2*(oh%4) + (ow%2); zero pad outside [0,720)x[0,1280).
// MFMA: A = weights (M=co16), B = pixels (N=16 even/odd ow), K=128 padded:
//   k = p*8 + j, p = ci*5+kh (0..14 real, 15 pad), j = kw (0..4 real, 5..7 pad).
// Dual-parity per wave; epilogue exchanges lane pairs (ds_swizzle xor-1) so each
// lane stores float4 of 4 consecutive ow -> 128B-dense dwordx4 store cohorts.

typedef __attribute__((ext_vector_type(8))) short bf16x8;
typedef __attribute__((ext_vector_type(4))) float f32x4;

static __device__ __forceinline__ unsigned short f2bf_rne(float f) {
    unsigned u = __builtin_bit_cast(unsigned, f);
    u += 0x7FFFu + ((u >> 16) & 1u);
    return (unsigned short)(u >> 16);
}

static __device__ __forceinline__ float swz_xor1(float v) {
    // BitMode: offset = (xor_mask<<10)|(or_mask<<5)|and_mask ; xor lane^1
    int r = __builtin_amdgcn_ds_swizzle(__builtin_bit_cast(int, v), 0x041F);
    return __builtin_bit_cast(float, r);
}

// wt2[s][p][co][j] bf16: 8*16*64*8 = 65536 elems = 128 KB
__global__ void wprep_kernel(const float* __restrict__ w, unsigned short* __restrict__ wt2) {
    int o = blockIdx.x * 256 + threadIdx.x;
    if (o >= 8 * 16 * 64 * 8) return;
    int j  = o & 7;
    int co = (o >> 3) & 63;
    int p  = (o >> 9) & 15;
    int s  = o >> 13;
    unsigned short v = 0;
    if (p < 15 && j < 5) {
        int ci = p / 5, kh = p % 5;
        v = f2bf_rne(w[((s * 64 + co) * 3 + ci) * 25 + kh * 5 + j]);
    }
    wt2[o] = v;
}

#define XS_W 264   // need 263 cols; even keeps float2 LDS reads 8B-aligned
#define XS_R 8     // x rows 4bh-2 .. 4bh+5

__global__ __launch_bounds__(256, 6)
void conv_mfma_kernel(const float* __restrict__ x, const unsigned short* __restrict__ wt2,
                      const float* __restrict__ bias, float* __restrict__ out) {
    const int zz  = blockIdx.z;
    const int b   = zz >> 2;
    const int cq  = zz & 3;            // co block: cq*16 .. cq*16+15
    const int bh  = blockIdx.y;        // output rows 4bh..4bh+3
    const int ow0 = blockIdx.x * 256;  // 256 output cols

    const int tid = threadIdx.x;
    __shared__ float xs[3 * XS_R * XS_W];   // 25344 B

    // ---- stage x tile (fp32, zero-padded halo) ----
    for (int idx = tid; idx < 3 * XS_R * XS_W; idx += 256) {
        int ci  = idx / (XS_R * XS_W);
        int rem = idx - ci * (XS_R * XS_W);
        int tt  = rem / XS_W;
        int u   = rem - tt * XS_W;
        int gr = 4 * bh - 2 + tt;
        int gc = ow0 - 2 + u;
        float v = 0.f;
        if ((unsigned)gr < 720u && (unsigned)gc < 1280u)
            v = x[((b * 3 + ci) * 720 + gr) * 1280 + gc];
        xs[idx] = v;
    }
    __syncthreads();

    const int r    = tid >> 6;     // wave id = output row phase 0..3
    const int lane = tid & 63;
    const int l15  = lane & 15;    // MFMA col = pixel index
    const int kg   = lane >> 4;    // k-octet / D co-subblock
    const int cob  = cq * 16;
    const int lodd = l15 & 1;      // lane parity within pair

    // ---- A (weight) fragments, both parities: 32 VGPRs ----
    bf16x8 Wf[2][4];
    #pragma unroll
    for (int c = 0; c < 2; ++c) {
        #pragma unroll
        for (int t = 0; t < 4; ++t) {
            int p = 4 * t + kg;
            int s = 2 * r + c;
            Wf[c][t] = *(const bf16x8*)(wt2 + ((size_t)((s * 16 + p) * 64) + cob + l15) * 8);
        }
    }

    // bias for D rows co_sub = 4*kg + reg
    float bv[2][4];
    #pragma unroll
    for (int c = 0; c < 2; ++c)
        #pragma unroll
        for (int reg = 0; reg < 4; ++reg)
            bv[c][reg] = bias[(2 * r + c) * 64 + cob + 4 * kg + reg];

    // LDS row offsets (floats) per t; pad group p==15 -> any valid row (weights zero)
    int rowoff[4];
    #pragma unroll
    for (int t = 0; t < 4; ++t) {
        int p  = 4 * t + kg;
        int pp = (p < 15) ? p : 0;
        int ci = pp / 5, kh = pp - 5 * ci;
        rowoff[t] = (ci * XS_R + r + kh) * XS_W;
    }

    const int oh = 4 * bh + r;
    // even lane stores co-planes 4kg+{0,1}, odd lane 4kg+{2,3}; both at ow pair-base
    const int coplane = cob + 4 * kg + 2 * lodd;
    float* opbase = out + ((size_t)(b * 64 + coplane) * 720 + oh) * 1280
                        + ow0 + 2 * (l15 & ~1);

    #pragma unroll 1
    for (int g = 0; g < 8; ++g) {
        f32x4 acc[2];
        #pragma unroll
        for (int c = 0; c < 2; ++c) {
            acc[c][0] = bv[c][0]; acc[c][1] = bv[c][1];
            acc[c][2] = bv[c][2]; acc[c][3] = bv[c][3];
        }

        const int colbase = 2 * l15 + 32 * g;
        #pragma unroll
        for (int t = 0; t < 4; ++t) {
            const float* ap = xs + rowoff[t] + colbase;
            float v0, v1, v2, v3, v4, v5, v6, v7, v8;
            { float2 f = *(const float2*)(ap + 0); v0 = f.x; v1 = f.y; }
            { float2 f = *(const float2*)(ap + 2); v2 = f.x; v3 = f.y; }
            { float2 f = *(const float2*)(ap + 4); v4 = f.x; v5 = f.y; }
            { float2 f = *(const float2*)(ap + 6); v6 = f.x; v7 = f.y; }
            { float2 f = *(const float2*)(ap + 8); v8 = f.x; }
            unsigned e0, e1, e2, e3, o0, o1, o2, o3;
            asm("v_cvt_pk_bf16_f32 %0, %1, %2" : "=v"(e0) : "v"(v0), "v"(v1));
            asm("v_cvt_pk_bf16_f32 %0, %1, %2" : "=v"(e1) : "v"(v2), "v"(v3));
            asm("v_cvt_pk_bf16_f32 %0, %1, %2" : "=v"(e2) : "v"(v4), "v"(v5));
            asm("v_cvt_pk_bf16_f32 %0, %1, %2" : "=v"(e3) : "v"(v6), "v"(v7));
            asm("v_cvt_pk_bf16_f32 %0, %1, %2" : "=v"(o0) : "v"(v1), "v"(v2));
            asm("v_cvt_pk_bf16_f32 %0, %1, %2" : "=v"(o1) : "v"(v3), "v"(v4));
            asm("v_cvt_pk_bf16_f32 %0, %1, %2" : "=v"(o2) : "v"(v5), "v"(v6));
            asm("v_cvt_pk_bf16_f32 %0, %1, %2" : "=v"(o3) : "v"(v7), "v"(v8));
            union { unsigned u[4]; bf16x8 v; } pe, po;
            pe.u[0] = e0; pe.u[1] = e1; pe.u[2] = e2; pe.u[3] = e3;
            po.u[0] = o0; po.u[1] = o1; po.u[2] = o2; po.u[3] = o3;
            acc[0] = __builtin_amdgcn_mfma_f32_16x16x32_bf16(Wf[0][t], pe.v, acc[0], 0, 0, 0);
            acc[1] = __builtin_amdgcn_mfma_f32_16x16x32_bf16(Wf[1][t], po.v, acc[1], 0, 0, 0);
        }

        // ---- pair exchange: even lane gets partner's (e,o) of regs 0,1;
        //      odd lane gets partner's (e,o) of regs 2,3 ----
        float pa = swz_xor1(lodd ? acc[0][0] : acc[0][2]);  // e of reg (even?0:2)
        float pb = swz_xor1(lodd ? acc[1][0] : acc[1][2]);  // o
        float pc = swz_xor1(lodd ? acc[0][1] : acc[0][3]);  // e of reg (even?1:3)
        float pd = swz_xor1(lodd ? acc[1][1] : acc[1][3]);  // o

        float* op = opbase + 32 * g;
        f32x4 st0, st1;
        if (!lodd) {
            st0[0] = acc[0][0]; st0[1] = acc[1][0]; st0[2] = pa; st0[3] = pb; // reg0
            st1[0] = acc[0][1]; st1[1] = acc[1][1]; st1[2] = pc; st1[3] = pd; // reg1
        } else {
            st0[0] = pa; st0[1] = pb; st0[2] = acc[0][2]; st0[3] = acc[1][2]; // reg2
            st1[0] = pc; st1[1] = pd; st1[2] = acc[0][3]; st1[3] = acc[1][3]; // reg3
        }
        *(f32x4*)(op) = st0;
        *(f32x4*)(op + (size_t)720 * 1280) = st1;
    }
}

extern "C" void kernel_launch(void* const* d_in, const int* in_sizes, int n_in,
                              void* d_out, int out_size, void* d_ws, size_t ws_size,
                              hipStream_t stream) {
    const float* x    = (const float*)d_in[0];
    const float* w    = (const float*)d_in[1];
    const float* bias = (const float*)d_in[2];
    float* out = (float*)d_out;
    unsigned short* wt2 = (unsigned short*)d_ws;  // 128 KB

    wprep_kernel<<<dim3(256), dim3(256), 0, stream>>>(w, wt2);

    dim3 grid(1280 / 256, 720 / 4, 8);   // (ow tiles, oh tiles, b*4 + co-quarter)
    conv_mfma_kernel<<<grid, dim3(256), 0, stream>>>(x, wt2, bias, out);
}

// Round 6
// 504.638 us; speedup vs baseline: 1.4160x; 1.0244x over previous
//
#include <hip/hip_runtime.h>

// out[b,co,oh,ow] = bias[s,co] + sum_{ci,kh,kw} x[b,ci,oh+kh-2,ow+kw-2]*w[s,co,ci,kh,kw]
//   s = 2*(oh%4) + (ow%2); zero pad outside [0,720)x[0,1280).
// MFMA: A = weights (M=co16), B = pixels (N=16 even/odd ow), K=128 padded:
//   k = p*8 + j, p = ci*5+kh (0..14 real, 15 pad), j = kw (0..4 real, 5..7 pad).
// x staged in LDS as BF16 (packed at load): even-parity frag = 4 raw dwords,
// odd-parity frag = v_alignbit of the same dwords (16-bit shift). Dual-parity
// per wave; epilogue pair-exchange -> dense dwordx4 stores.

typedef __attribute__((ext_vector_type(8))) short bf16x8;
typedef __attribute__((ext_vector_type(4))) float f32x4;

static __device__ __forceinline__ unsigned short f2bf_rne(float f) {
    unsigned u = __builtin_bit_cast(unsigned, f);
    u += 0x7FFFu + ((u >> 16) & 1u);
    return (unsigned short)(u >> 16);
}

static __device__ __forceinline__ float swz_xor1(float v) {
    // BitMode: offset = (xor<<10)|(or<<5)|and ; xor lane^1
    int r = __builtin_amdgcn_ds_swizzle(__builtin_bit_cast(int, v), 0x041F);
    return __builtin_bit_cast(float, r);
}

// wt2[s][p][co][j] bf16: 8*16*64*8 = 65536 elems = 128 KB
__global__ void wprep_kernel(const float* __restrict__ w, unsigned short* __restrict__ wt2) {
    int o = blockIdx.x * 256 + threadIdx.x;
    if (o >= 8 * 16 * 64 * 8) return;
    int j  = o & 7;
    int co = (o >> 3) & 63;
    int p  = (o >> 9) & 15;
    int s  = o >> 13;
    unsigned short v = 0;
    if (p < 15 && j < 5) {
        int ci = p / 5, kh = p % 5;
        v = f2bf_rne(w[((s * 64 + co) * 3 + ci) * 25 + kh * 5 + j]);
    }
    wt2[o] = v;
}

#define ROWDW 136              // LDS row stride in dwords (272 bf16; bank delta 8)
#define ROWB  (ROWDW * 4)      // 544 B
#define NROWS 24               // 3 ci * 8 x-rows
#define NDW   (NROWS * ROWDW)  // 3264 dwords = 13056 B

__global__ __launch_bounds__(256, 6)
void conv_mfma_kernel(const float* __restrict__ x, const unsigned short* __restrict__ wt2,
                      const float* __restrict__ bias, float* __restrict__ out) {
    const int zz  = blockIdx.z;
    const int b   = zz >> 2;
    const int cq  = zz & 3;            // co block: cq*16 .. cq*16+15
    const int bh  = blockIdx.y;        // output rows 4bh..4bh+3
    const int ow0 = blockIdx.x * 256;  // 256 output cols

    const int tid = threadIdx.x;
    __shared__ unsigned xs[NDW];       // bf16 pairs, 13056 B

    // ---- stage x tile as bf16 (cols ow0-4 .. ; gc even => float2 pred is both-or-neither) ----
    #pragma unroll
    for (int it = 0; it < 13; ++it) {
        int dw = tid + it * 256;
        if (dw < NDW) {
            int row = dw / ROWDW;          // magic-mul
            int u   = dw - row * ROWDW;
            int ci  = row >> 3;
            int rin = row & 7;
            int gr  = 4 * bh - 2 + rin;
            int gc  = ow0 - 4 + 2 * u;     // even, float2-aligned
            unsigned pk = 0;
            if ((unsigned)gr < 720u && (unsigned)gc < 1280u) {
                float2 f = *(const float2*)(x + ((size_t)(b * 3 + ci) * 720 + gr) * 1280 + gc);
                asm("v_cvt_pk_bf16_f32 %0, %1, %2" : "=v"(pk) : "v"(f.x), "v"(f.y));
            }
            xs[dw] = pk;
        }
    }
    __syncthreads();

    const int r    = tid >> 6;     // wave id = output row phase 0..3
    const int lane = tid & 63;
    const int l15  = lane & 15;
    const int kg   = lane >> 4;    // k-octet / D co-subblock
    const int cob  = cq * 16;
    const int lodd = l15 & 1;

    // ---- A (weight) fragments, both parities: 32 VGPRs ----
    bf16x8 Wf[2][4];
    #pragma unroll
    for (int c = 0; c < 2; ++c) {
        #pragma unroll
        for (int t = 0; t < 4; ++t) {
            int p = 4 * t + kg;
            int s = 2 * r + c;
            Wf[c][t] = *(const bf16x8*)(wt2 + ((size_t)((s * 16 + p) * 64) + cob + l15) * 8);
        }
    }

    float bv[2][4];
    #pragma unroll
    for (int c = 0; c < 2; ++c)
        #pragma unroll
        for (int reg = 0; reg < 4; ++reg)
            bv[c][reg] = bias[(2 * r + c) * 64 + cob + 4 * kg + reg];

    // per-t LDS row byte offsets; pad group p==15 -> row 0 (weights zero, data finite)
    int rowbyte[4];
    #pragma unroll
    for (int t = 0; t < 4; ++t) {
        int p  = 4 * t + kg;
        int pp = (p < 15) ? p : 0;
        int ci = pp / 5, kh = pp - 5 * ci;
        rowbyte[t] = (ci * 8 + r + kh) * ROWB;
    }

    const int oh = 4 * bh + r;
    const int coplane = cob + 4 * kg + 2 * lodd;
    float* opbase = out + ((size_t)(b * 64 + coplane) * 720 + oh) * 1280
                        + ow0 + 2 * (l15 & ~1);
    const unsigned char* xsb = (const unsigned char*)xs;

    #pragma unroll 1
    for (int g = 0; g < 8; ++g) {
        f32x4 acc[2];
        #pragma unroll
        for (int c = 0; c < 2; ++c) {
            acc[c][0] = bv[c][0]; acc[c][1] = bv[c][1];
            acc[c][2] = bv[c][2]; acc[c][3] = bv[c][3];
        }

        const int colB = 4 * l15 + 64 * g + 4;   // dword-aligned byte offset in row
        #pragma unroll
        for (int t = 0; t < 4; ++t) {
            const unsigned* dp = (const unsigned*)(xsb + rowbyte[t] + colB);
            unsigned d0 = dp[0], d1 = dp[1], d2 = dp[2], d3 = dp[3], d4 = dp[4];
            union { unsigned u[4]; bf16x8 v; } fe, fo;
            fe.u[0] = d0; fe.u[1] = d1; fe.u[2] = d2; fe.u[3] = d3;
            fo.u[0] = __builtin_amdgcn_alignbit(d1, d0, 16);
            fo.u[1] = __builtin_amdgcn_alignbit(d2, d1, 16);
            fo.u[2] = __builtin_amdgcn_alignbit(d3, d2, 16);
            fo.u[3] = __builtin_amdgcn_alignbit(d4, d3, 16);
            acc[0] = __builtin_amdgcn_mfma_f32_16x16x32_bf16(Wf[0][t], fe.v, acc[0], 0, 0, 0);
            acc[1] = __builtin_amdgcn_mfma_f32_16x16x32_bf16(Wf[1][t], fo.v, acc[1], 0, 0, 0);
        }

        // ---- pair exchange: even lane keeps regs 0,1; odd lane keeps regs 2,3 ----
        float pa = swz_xor1(lodd ? acc[0][0] : acc[0][2]);
        float pb = swz_xor1(lodd ? acc[1][0] : acc[1][2]);
        float pc = swz_xor1(lodd ? acc[0][1] : acc[0][3]);
        float pd = swz_xor1(lodd ? acc[1][1] : acc[1][3]);

        float* op = opbase + 32 * g;
        f32x4 st0, st1;
        if (!lodd) {
            st0[0] = acc[0][0]; st0[1] = acc[1][0]; st0[2] = pa; st0[3] = pb; // reg0 plane
            st1[0] = acc[0][1]; st1[1] = acc[1][1]; st1[2] = pc; st1[3] = pd; // reg1 plane
        } else {
            st0[0] = pa; st0[1] = pb; st0[2] = acc[0][2]; st0[3] = acc[1][2]; // reg2 plane
            st1[0] = pc; st1[1] = pd; st1[2] = acc[0][3]; st1[3] = acc[1][3]; // reg3 plane
        }
        *(f32x4*)(op) = st0;
        *(f32x4*)(op + (size_t)720 * 1280) = st1;
    }
}

extern "C" void kernel_launch(void* const* d_in, const int* in_sizes, int n_in,
                              void* d_out, int out_size, void* d_ws, size_t ws_size,
                              hipStream_t stream) {
    const float* x    = (const float*)d_in[0];
    const float* w    = (const float*)d_in[1];
    const float* bias = (const float*)d_in[2];
    float* out = (float*)d_out;
    unsigned short* wt2 = (unsigned short*)d_ws;  // 128 KB

    wprep_kernel<<<dim3(256), dim3(256), 0, stream>>>(w, wt2);

    dim3 grid(1280 / 256, 720 / 4, 8);   // (ow tiles, oh tiles, b*4 + co-quarter)
    conv_mfma_kernel<<<grid, dim3(256), 0, stream>>>(x, wt2, bias, out);
}